// Round 16
// baseline (423.985 us; speedup 1.0000x reference)
//
#include <hip/hip_runtime.h>
#include <math.h>

// ---------------- problem constants ----------------
#define TOK   100352            // B * H * W  = 32*56*56  (= B_ * N = 2048*49)
#define OUTCH 19267584L         // TOK * 192, elements per output chunk (f32)
#define NWIN  2048

typedef __attribute__((ext_vector_type(4))) float f32x4;
typedef __attribute__((ext_vector_type(8))) short bf16x8;
typedef __attribute__((ext_vector_type(4))) unsigned short u16x4;

__device__ __forceinline__ unsigned short f2bf(float f) {
    unsigned u = __builtin_bit_cast(unsigned, f);
    u += 0x7FFFu + ((u >> 16) & 1u);          // round-to-nearest-even
    return (unsigned short)(u >> 16);
}
__device__ __forceinline__ float bf2f(unsigned short s) {
    return __builtin_bit_cast(float, (unsigned)s << 16);
}

// ---------------- weight prep: all four weight matrices MFMA fragment-packed ----------------
// wt layout (bf16):
//  [0,110592)        qkvp6: 216 slots instr=((s*6+h)*2+ni)*6+ks  (6-wave attn kernel; s<3,h<6,ni<2)
//  [110592,147456)   projp6: 72 slots instr=((h*2+ni)*6+ks), h<6
//  [147456,294912)   w1p:  288 slots  instr=((s*4+wv)*3+ni)*6+ks, s<4
//  [294912,442368)   w2p:  288 slots  (same index, k runs over 768)
// Each slot = 512 bf16 = lane*8+j  -> wave load = coalesced 1 KB.
__global__ __launch_bounds__(256) void k_prep_w(const float* __restrict__ qkv_w,
                                                const float* __restrict__ proj_w,
                                                const float* __restrict__ fc1_w,
                                                const float* __restrict__ fc2_w,
                                                unsigned short* __restrict__ wt)
{
    int i = blockIdx.x * 256 + threadIdx.x;   // grid covers exactly 442368
    float v;
    if (i < 110592) {
        int instr = i >> 9, rem = i & 511, lane = rem >> 3, j = rem & 7;
        int ks = instr % 6, t = instr / 6;
        int ni = t & 1, t2 = t >> 1;                         // t2 = s*6+h in [0,18)
        int hh = t2 % 6, s = t2 / 6;
        int n = s * 192 + hh * 32 + ni * 16 + (lane & 15);   // out col in [0,576)
        int k = ks * 32 + ((lane >> 4) << 3) + j;            // k in [0,192)
        v = qkv_w[k * 576 + n];
    } else if (i < 147456) {
        int j2 = i - 110592;
        int instr = j2 >> 9, rem = j2 & 511, lane = rem >> 3, j = rem & 7;
        int ks = instr % 6, t = instr / 6;                   // t in [0,12)
        int ni = t & 1, hh = t >> 1;                         // ni<2, head hh<6
        int n = hh * 32 + ni * 16 + (lane & 15);             // out col in [0,192)
        int k = ks * 32 + ((lane >> 4) << 3) + j;
        v = proj_w[k * 192 + n];
    } else if (i < 294912) {
        int j2 = i - 147456;
        int instr = j2 >> 9, rem = j2 & 511, lane = rem >> 3, j = rem & 7;
        int ks = instr % 6, t = instr / 6;
        int ni = t % 3, t2 = t / 3;
        int wv = t2 & 3, s = t2 >> 2;
        int n = s * 192 + wv * 48 + ni * 16 + (lane & 15);   // fc1 out col in [0,768)
        int k = ks * 32 + ((lane >> 4) << 3) + j;            // k in [0,192)
        v = fc1_w[k * 768 + n];
    } else {
        int j2 = i - 294912;
        int instr = j2 >> 9, rem = j2 & 511, lane = rem >> 3, j = rem & 7;
        int ks = instr % 6, t = instr / 6;
        int ni = t % 3, t2 = t / 3;
        int wv = t2 & 3, s = t2 >> 2;
        int n = wv * 48 + ni * 16 + (lane & 15);             // fc2 out col in [0,192)
        int k = s * 192 + ks * 32 + ((lane >> 4) << 3) + j;  // hidden in [0,768)
        v = fc2_w[k * 192 + n];
    }
    wt[i] = f2bf(v);
}

// ---------------- fused MLP: xo = xv + fc2(gelu(fc1(h2))) + b2 (single write) ----------------
__global__ __launch_bounds__(256) void k_mlp(const unsigned short* __restrict__ h2,
                                             const unsigned short* __restrict__ w1p,
                                             const float* __restrict__ b1,
                                             const unsigned short* __restrict__ w2p,
                                             const float* __restrict__ b2,
                                             const unsigned short* __restrict__ xv,
                                             float* __restrict__ xo)
{
    __shared__ unsigned short lA[64 * 192];   // h2 tile, swizzled
    __shared__ unsigned short lH[64 * 192];   // gelu(fc1) slab, swizzled
    const int tid = threadIdx.x, lane = tid & 63, wv = tid >> 6;
    const long m0 = (long)blockIdx.x * 64;

    #pragma unroll
    for (int c = tid; c < 64 * 24; c += 256) {
        int row = c / 24, k16 = c - row * 24;
        bf16x8 v = *(const bf16x8*)(h2 + (m0 + row) * 192 + k16 * 8);
        *(bf16x8*)((char*)lA + row * 384 + ((k16 * 16) ^ ((row & 7) << 4))) = v;
    }

    f32x4 acc2[4][3];
    #pragma unroll
    for (int mi = 0; mi < 4; mi++)
        #pragma unroll
        for (int ni = 0; ni < 3; ni++) acc2[mi][ni] = (f32x4){0.f, 0.f, 0.f, 0.f};
    __syncthreads();

    for (int s = 0; s < 4; s++) {
        f32x4 acc1[4][3];
        #pragma unroll
        for (int mi = 0; mi < 4; mi++)
            #pragma unroll
            for (int ni = 0; ni < 3; ni++) acc1[mi][ni] = (f32x4){0.f, 0.f, 0.f, 0.f};
        #pragma unroll
        for (int ks = 0; ks < 6; ks++) {
            int kb = ks * 64 + ((lane >> 4) << 4);
            bf16x8 bfr[3];
            #pragma unroll
            for (int ni = 0; ni < 3; ni++) {
                int instr = ((s * 4 + wv) * 3 + ni) * 6 + ks;
                bfr[ni] = *(const bf16x8*)(w1p + (instr << 9) + (lane << 3));
            }
            #pragma unroll
            for (int mi = 0; mi < 4; mi++) {
                int row = mi * 16 + (lane & 15);
                bf16x8 afr = *(const bf16x8*)((char*)lA + row * 384 + (kb ^ ((row & 7) << 4)));
                #pragma unroll
                for (int ni = 0; ni < 3; ni++)
                    acc1[mi][ni] = __builtin_amdgcn_mfma_f32_16x16x32_bf16(afr, bfr[ni], acc1[mi][ni], 0, 0, 0);
            }
        }
        __syncthreads();     // previous slab's GEMM2 reads of lH are done
        #pragma unroll
        for (int mi = 0; mi < 4; mi++)
            #pragma unroll
            for (int ni = 0; ni < 3; ni++) {
                int col = wv * 48 + ni * 16 + (lane & 15);
                float bv = b1[s * 192 + col];
                #pragma unroll
                for (int r = 0; r < 4; r++) {
                    int row = mi * 16 + ((lane >> 4) << 2) + r;
                    float v = acc1[mi][ni][r] + bv;
                    // tanh-form GELU via fast sigmoid: v * sigma(1.5957691*(v + 0.044715 v^3))
                    float u = v + 0.044715f * v * v * v;
                    float ge = v / (1.f + __expf(-1.5957691216057308f * u));
                    *(unsigned short*)((char*)lH + row * 384 + ((2 * col) ^ ((row & 7) << 4))) = f2bf(ge);
                }
            }
        __syncthreads();
        #pragma unroll
        for (int ks = 0; ks < 6; ks++) {
            int kb = ks * 64 + ((lane >> 4) << 4);
            bf16x8 bfr[3];
            #pragma unroll
            for (int ni = 0; ni < 3; ni++) {
                int instr = ((s * 4 + wv) * 3 + ni) * 6 + ks;
                bfr[ni] = *(const bf16x8*)(w2p + (instr << 9) + (lane << 3));
            }
            #pragma unroll
            for (int mi = 0; mi < 4; mi++) {
                int row = mi * 16 + (lane & 15);
                bf16x8 afr = *(const bf16x8*)((char*)lH + row * 384 + (kb ^ ((row & 7) << 4)));
                #pragma unroll
                for (int ni = 0; ni < 3; ni++)
                    acc2[mi][ni] = __builtin_amdgcn_mfma_f32_16x16x32_bf16(afr, bfr[ni], acc2[mi][ni], 0, 0, 0);
            }
        }
    }
    #pragma unroll
    for (int mi = 0; mi < 4; mi++)
        #pragma unroll
        for (int ni = 0; ni < 3; ni++) {
            int gcol = wv * 48 + ni * 16 + (lane & 15);
            float bv = b2[gcol];
            #pragma unroll
            for (int r = 0; r < 4; r++) {
                long grow = m0 + mi * 16 + ((lane >> 4) << 2) + r;
                xo[grow * 192 + gcol] = bf2f(xv[grow * 192 + gcol]) + acc2[mi][ni][r] + bv;
            }
        }
}

// ---------------- mega-fused: LN1 + QKV + attention + proj + LN2 ----------------
// One block (6 waves = 6 heads) per window. LDS map (136,424 B, 1 block/CU):
//   [0, 78800)        phase A: lA (LN1'd input, 18.8 KB, swizzled) then ATT f32 [6][49][67]
//                     phase C: PO (18.8 KB swizzled) + xoT f32 [49][196] at +19200
//   [78800, 97616)    qL bf16 49x192 swizzled (384 B rows)
//   [97616, 116432)   kL bf16 49x192 swizzled
//   [116432, 136424)  vL bf16 49 rows x 408 B stride (unswizzled, 8B-aligned rows)
#define ATS 67
#define QL_OFF 78800
#define KL_OFF 97616
#define VL_OFF 116432
__global__ __launch_bounds__(384) void k_attn(const float* __restrict__ x,
                                              const float* __restrict__ n1g,
                                              const float* __restrict__ n1b,
                                              const unsigned short* __restrict__ qkvp,
                                              const float* __restrict__ qbias,
                                              const float* __restrict__ rpb,
                                              const float* __restrict__ plw,
                                              const float* __restrict__ plb,
                                              const float* __restrict__ pww,
                                              const float* __restrict__ pwb,
                                              const unsigned short* __restrict__ projp,
                                              const float* __restrict__ pbias,
                                              const float* __restrict__ g2,
                                              const float* __restrict__ b2,
                                              float* __restrict__ outq,           // q chunk; k,v at +OUTCH,+2*OUTCH
                                              unsigned short* __restrict__ xv,
                                              unsigned short* __restrict__ h2)
{
    __shared__ __align__(16) char SM[136424];
    float (*ATT)[49][ATS] = (float(*)[49][ATS])SM;
    float (*xoT)[196]     = (float(*)[196])(SM + 19200);

    int w = blockIdx.x, widx = w & 63;
    int tid = threadIdx.x, lane = tid & 63, h = tid >> 6;   // wave id == head
    int wi = widx >> 3, wj = widx & 7, bb = w >> 6;
    const long rowbase = (long)w * 49;
    const bool bdry = (wi == 7) || (wj == 7);

    // ---- Phase 1: LN1 + roll(-3,-3) gather -> lA (rows 0..48, swizzled) ----
    if (tid < 196) {
        int r = tid >> 2, c0 = (tid & 3) * 48;
        int rr = r / 7, ss = r - rr * 7;
        int hh = wi * 7 + rr + 3; if (hh >= 56) hh -= 56;
        int ww = wj * 7 + ss + 3; if (ww >= 56) ww -= 56;
        const f32x4* sp = (const f32x4*)(x + ((long)(bb * 56 + hh) * 56 + ww) * 192 + c0);
        f32x4 vv[12];
        float sum = 0.f, sq = 0.f;
        #pragma unroll
        for (int i = 0; i < 12; i++) {
            vv[i] = sp[i];
            #pragma unroll
            for (int j = 0; j < 4; j++) { sum += vv[i][j]; sq += vv[i][j] * vv[i][j]; }
        }
        sum += __shfl_xor(sum, 1); sq += __shfl_xor(sq, 1);
        sum += __shfl_xor(sum, 2); sq += __shfl_xor(sq, 2);
        float mu = sum * (1.f / 192.f);
        float rs = rsqrtf(sq * (1.f / 192.f) - mu * mu + 1e-5f);
        #pragma unroll
        for (int i = 0; i < 6; i++) {
            bf16x8 o8;
            #pragma unroll
            for (int j = 0; j < 8; j++) {
                int idx = i * 8 + j, c = c0 + idx;
                o8[j] = (short)f2bf((vv[idx >> 2][idx & 3] - mu) * rs * n1g[c] + n1b[c]);
            }
            *(bf16x8*)(SM + r * 384 + ((2 * (c0 + i * 8)) ^ ((r & 7) << 4))) = o8;
        }
    }
    __syncthreads();

    // ---- Phase 2: QKV GEMM; wave h computes head h's 32 cols of q,k,v ----
    f32x4 aq[4][2], ak[4][2], av[4][2];
    #pragma unroll
    for (int mi = 0; mi < 4; mi++)
        #pragma unroll
        for (int ni = 0; ni < 2; ni++) {
            aq[mi][ni] = (f32x4){0.f, 0.f, 0.f, 0.f};
            ak[mi][ni] = (f32x4){0.f, 0.f, 0.f, 0.f};
            av[mi][ni] = (f32x4){0.f, 0.f, 0.f, 0.f};
        }
    #pragma unroll
    for (int ks = 0; ks < 6; ks++) {
        int kb = ks * 64 + ((lane >> 4) << 4);
        bf16x8 afr[4];
        #pragma unroll
        for (int mi = 0; mi < 4; mi++) {
            int row = mi * 16 + (lane & 15);                 // rows 49..63 read garbage (outputs discarded)
            afr[mi] = *(const bf16x8*)(SM + row * 384 + (kb ^ ((row & 7) << 4)));
        }
        bf16x8 bq[2], bk[2], bv[2];
        #pragma unroll
        for (int ni = 0; ni < 2; ni++) {
            bq[ni] = *(const bf16x8*)(qkvp + (((((0 * 6 + h) * 2 + ni) * 6 + ks)) << 9) + (lane << 3));
            bk[ni] = *(const bf16x8*)(qkvp + (((((1 * 6 + h) * 2 + ni) * 6 + ks)) << 9) + (lane << 3));
            bv[ni] = *(const bf16x8*)(qkvp + (((((2 * 6 + h) * 2 + ni) * 6 + ks)) << 9) + (lane << 3));
        }
        #pragma unroll
        for (int mi = 0; mi < 4; mi++)
            #pragma unroll
            for (int ni = 0; ni < 2; ni++) {
                aq[mi][ni] = __builtin_amdgcn_mfma_f32_16x16x32_bf16(afr[mi], bq[ni], aq[mi][ni], 0, 0, 0);
                ak[mi][ni] = __builtin_amdgcn_mfma_f32_16x16x32_bf16(afr[mi], bk[ni], ak[mi][ni], 0, 0, 0);
                av[mi][ni] = __builtin_amdgcn_mfma_f32_16x16x32_bf16(afr[mi], bv[ni], av[mi][ni], 0, 0, 0);
            }
    }
    __syncthreads();     // lA reads complete (qL region aliases nothing; lA at [0,18816) stays until Phase 3)

    // epilogue: bf16 LDS copies only (global writeback is a separate coalesced phase)
    #pragma unroll
    for (int mi = 0; mi < 4; mi++)
        #pragma unroll
        for (int ni = 0; ni < 2; ni++) {
            int col = h * 32 + ni * 16 + (lane & 15);
            float bgq = qbias[col], bgk = qbias[192 + col], bgv = qbias[384 + col];
            #pragma unroll
            for (int r = 0; r < 4; r++) {
                int m = mi * 16 + ((lane >> 4) << 2) + r;
                if (m < 49) {
                    int sw = (2 * col) ^ ((m & 7) << 4);
                    *(unsigned short*)(SM + QL_OFF + m * 384 + sw) = f2bf(aq[mi][ni][r] + bgq);
                    *(unsigned short*)(SM + KL_OFF + m * 384 + sw) = f2bf(ak[mi][ni][r] + bgk);
                    *(unsigned short*)(SM + VL_OFF + m * 408 + 2 * col) = f2bf(av[mi][ni][r] + bgv);
                }
            }
        }
    __syncthreads();

    // ---- Phase 2b: coalesced f32 writeback of q/k/v from LDS (1 KB/wave-iteration) ----
    {
        float* qout = outq + rowbase * 192;
        for (int c = tid; c < 2352; c += 384) {              // 2352 = 49*192/4 quads
            int e = c << 2, m = e / 192, col0 = e - m * 192; // col0 multiple of 4
            int sw = (2 * col0) ^ ((m & 7) << 4);
            u16x4 qv = *(const u16x4*)(SM + QL_OFF + m * 384 + sw);
            u16x4 kv = *(const u16x4*)(SM + KL_OFF + m * 384 + sw);
            u16x4 vv = *(const u16x4*)(SM + VL_OFF + m * 408 + 2 * col0);
            f32x4 qf, kf, vf;
            #pragma unroll
            for (int j = 0; j < 4; j++) { qf[j] = bf2f(qv[j]); kf[j] = bf2f(kv[j]); vf[j] = bf2f(vv[j]); }
            *(f32x4*)(qout + e) = qf;
            *(f32x4*)(qout + OUTCH + e) = kf;
            *(f32x4*)(qout + 2 * OUTCH + e) = vf;
        }
    }

    // ---- Phase 3: zero ATT pad cols [49,64) (lA dead; ATT region fresh) ----
    for (int c = tid; c < 6 * 49 * 15; c += 384) {
        int g = c / (49 * 15), rem = c - g * (49 * 15);
        int m = rem / 15, n = 49 + (rem - m * 15);
        ATT[g][m][n] = 0.f;
    }

    // ---- Phase 4: QK^T from qL/kL (b128 swizzled fragment reads) ----
    bf16x8 qfr[4], kfr[4];
    #pragma unroll
    for (int mi = 0; mi < 4; mi++) {
        int m = mi * 16 + (lane & 15); if (m > 48) m = 48;
        qfr[mi] = *(const bf16x8*)(SM + QL_OFF + m * 384 + ((h * 64 + ((lane >> 4) << 4)) ^ ((m & 7) << 4)));
    }
    #pragma unroll
    for (int ni = 0; ni < 4; ni++) {
        int n = ni * 16 + (lane & 15); if (n > 48) n = 48;
        kfr[ni] = *(const bf16x8*)(SM + KL_OFF + n * 384 + ((h * 64 + ((lane >> 4) << 4)) ^ ((n & 7) << 4)));
    }
    f32x4 sa[4][4];
    #pragma unroll
    for (int ni = 0; ni < 4; ni++)
        #pragma unroll
        for (int mi = 0; mi < 4; mi++)
            sa[mi][ni] = __builtin_amdgcn_mfma_f32_16x16x32_bf16(qfr[mi], kfr[ni], (f32x4){0.f, 0.f, 0.f, 0.f}, 0, 0, 0);
    const float scale = 0.17677669529663687f;   // 32^-0.5
    #pragma unroll
    for (int mi = 0; mi < 4; mi++)
        #pragma unroll
        for (int ni = 0; ni < 4; ni++)
            #pragma unroll
            for (int r = 0; r < 4; r++) {
                int m = mi * 16 + ((lane >> 4) << 2) + r, n = ni * 16 + (lane & 15);
                if (m < 49 && n < 49) {
                    int rq = m / 7, cq = m - rq * 7, rk = n / 7, ck = n - rk * 7;
                    int ridx = (rq - rk + 6) * 13 + (cq - ck + 6);
                    ATT[h][m][n] = sa[mi][ni][r] * scale + rpb[ridx * 6 + h];
                }
            }
    __syncthreads();

    // ---- Phase 5: pl head-mix + shift mask (in place; interior windows skip mask) ----
    for (int p = tid; p < 2401; p += 384) {
        int m = p / 49, n = p - m * 49;
        float a[6];
        #pragma unroll
        for (int g = 0; g < 6; g++) a[g] = ATT[g][m][n];
        float msk = 0.f;
        if (bdry) {
            int rq = m / 7, cq = m - rq * 7, rk = n / 7, ck = n - rk * 7;
            int ghq = wi * 7 + rq, gwq = wj * 7 + cq, ghk = wi * 7 + rk, gwk = wj * 7 + ck;
            int regq = (ghq < 49 ? 0 : (ghq < 53 ? 1 : 2)) * 3 + (gwq < 49 ? 0 : (gwq < 53 ? 1 : 2));
            int regk = (ghk < 49 ? 0 : (ghk < 53 ? 1 : 2)) * 3 + (gwk < 49 ? 0 : (gwk < 53 ? 1 : 2));
            msk = (regq != regk) ? -100.f : 0.f;
        }
        #pragma unroll
        for (int g = 0; g < 6; g++) {
            float v = plb[g] + msk;
            #pragma unroll
            for (int h2i = 0; h2i < 6; h2i++) v += a[h2i] * plw[h2i * 6 + g];
            ATT[g][m][n] = v;
        }
    }
    __syncthreads();

    // ---- Phase 6: softmax, row-per-lane ----
    if (tid < 294) {
        int g = tid / 49, m = tid - g * 49;
        float* row = &ATT[g][m][0];
        float mx = row[0];
        #pragma unroll
        for (int j = 1; j < 49; j++) mx = fmaxf(mx, row[j]);
        float e[49]; float sm = 0.f;
        #pragma unroll
        for (int j = 0; j < 49; j++) { e[j] = __expf(row[j] - mx); sm += e[j]; }
        float inv = 1.f / sm;
        #pragma unroll
        for (int j = 0; j < 49; j++) row[j] = e[j] * inv;
    }
    __syncthreads();

    // ---- Phase 7: pw head-mix (in place) ----
    for (int p = tid; p < 2401; p += 384) {
        int m = p / 49, n = p - m * 49;
        float a[6];
        #pragma unroll
        for (int g = 0; g < 6; g++) a[g] = ATT[g][m][n];
        #pragma unroll
        for (int g = 0; g < 6; g++) {
            float v = pwb[g];
            #pragma unroll
            for (int h2i = 0; h2i < 6; h2i++) v += a[h2i] * pww[h2i * 6 + g];
            ATT[g][m][n] = v;
        }
    }
    __syncthreads();

    // ---- Phase 8: PV (P-frags from ATT, V-frags from vL) ----
    bf16x8 vfr[2][2];
    #pragma unroll
    for (int kst = 0; kst < 2; kst++)
        #pragma unroll
        for (int ni = 0; ni < 2; ni++) {
            int d = h * 32 + ni * 16 + (lane & 15);
            #pragma unroll
            for (int j = 0; j < 8; j++) {
                int n = kst * 32 + ((lane >> 4) << 3) + j; if (n > 48) n = 48;
                vfr[kst][ni][j] = *(const unsigned short*)(SM + VL_OFF + n * 408 + 2 * d);
            }
        }
    f32x4 oa[4][2];
    #pragma unroll
    for (int mi = 0; mi < 4; mi++)
        #pragma unroll
        for (int ni = 0; ni < 2; ni++) oa[mi][ni] = (f32x4){0.f, 0.f, 0.f, 0.f};
    #pragma unroll
    for (int kst = 0; kst < 2; kst++) {
        #pragma unroll
        for (int mi = 0; mi < 4; mi++) {
            int m = mi * 16 + (lane & 15); if (m > 48) m = 48;
            const float* ap = &ATT[h][m][kst * 32 + ((lane >> 4) << 3)];
            bf16x8 afr;
            #pragma unroll
            for (int j = 0; j < 8; j++) afr[j] = (short)f2bf(ap[j]);
            #pragma unroll
            for (int ni = 0; ni < 2; ni++)
                oa[mi][ni] = __builtin_amdgcn_mfma_f32_16x16x32_bf16(afr, vfr[kst][ni], oa[mi][ni], 0, 0, 0);
        }
    }
    __syncthreads();                         // all ATT reads done; region reusable

    // ---- Phase 9: PV-out -> PO (bf16, swizzled) in dead ATT space ----
    #pragma unroll
    for (int mi = 0; mi < 4; mi++)
        #pragma unroll
        for (int ni = 0; ni < 2; ni++)
            #pragma unroll
            for (int r = 0; r < 4; r++) {
                int m = mi * 16 + ((lane >> 4) << 2) + r;
                if (m < 49) {
                    int col = h * 32 + ni * 16 + (lane & 15);
                    *(unsigned short*)(SM + m * 384 + ((2 * col) ^ ((m & 7) << 4))) = f2bf(oa[mi][ni][r]);
                }
            }
    __syncthreads();

    // ---- Phase 9b: T14 prefetch of residual x (hides HBM latency under proj GEMM) ----
    float xpre[4][2][4];
    #pragma unroll
    for (int mi = 0; mi < 4; mi++)
        #pragma unroll
        for (int ni = 0; ni < 2; ni++) {
            int gc = h * 32 + ni * 16 + (lane & 15);
            #pragma unroll
            for (int r = 0; r < 4; r++) {
                int m = mi * 16 + ((lane >> 4) << 2) + r;
                xpre[mi][ni][r] = 0.f;
                if (m < 49) {
                    int rr = m / 7, ss = m - rr * 7;
                    int ho = wi * 7 + rr + 3; if (ho >= 56) ho -= 56;     // roll(+SHIFT)
                    int wo = wj * 7 + ss + 3; if (wo >= 56) wo -= 56;
                    long tp = ((long)(bb * 56 + ho) * 56 + wo);
                    xpre[mi][ni][r] = x[tp * 192 + gc];
                }
            }
        }

    // ---- Phase 10: proj GEMM (wave h -> cols h*32..+32) ----
    f32x4 pacc[4][2];
    #pragma unroll
    for (int mi = 0; mi < 4; mi++)
        #pragma unroll
        for (int ni = 0; ni < 2; ni++) pacc[mi][ni] = (f32x4){0.f, 0.f, 0.f, 0.f};
    #pragma unroll
    for (int ks = 0; ks < 6; ks++) {
        int kb = ks * 64 + ((lane >> 4) << 4);
        bf16x8 bfr[2];
        #pragma unroll
        for (int ni = 0; ni < 2; ni++) {
            int instr = (h * 2 + ni) * 6 + ks;
            bfr[ni] = *(const bf16x8*)(projp + (instr << 9) + (lane << 3));
        }
        #pragma unroll
        for (int mi = 0; mi < 4; mi++) {
            int row = mi * 16 + (lane & 15); if (row > 48) row = 48;
            bf16x8 afr = *(const bf16x8*)(SM + row * 384 + (kb ^ ((row & 7) << 4)));
            #pragma unroll
            for (int ni = 0; ni < 2; ni++)
                pacc[mi][ni] = __builtin_amdgcn_mfma_f32_16x16x32_bf16(afr, bfr[ni], pacc[mi][ni], 0, 0, 0);
        }
    }

    // ---- Phase 11: residual combine -> xoT[m][gc] (x prefetched in 9b) ----
    #pragma unroll
    for (int mi = 0; mi < 4; mi++)
        #pragma unroll
        for (int ni = 0; ni < 2; ni++) {
            int gc = h * 32 + ni * 16 + (lane & 15);
            float bv = pbias[gc];
            #pragma unroll
            for (int r = 0; r < 4; r++) {
                int m = mi * 16 + ((lane >> 4) << 2) + r;
                if (m < 49)
                    xoT[m][gc] = xpre[mi][ni][r] + pacc[mi][ni][r] + bv;
            }
        }
    __syncthreads();

    // ---- Phase 12: LN2 + spatial writes of h2 and xv (bf16) ----
    if (tid < 196) {
        int m = tid >> 2, c0 = (tid & 3) * 48;
        float vv[48];
        float sum = 0.f, sq = 0.f;
        #pragma unroll
        for (int i = 0; i < 48; i++) { vv[i] = xoT[m][c0 + i]; sum += vv[i]; sq += vv[i] * vv[i]; }
        sum += __shfl_xor(sum, 1); sq += __shfl_xor(sq, 1);
        sum += __shfl_xor(sum, 2); sq += __shfl_xor(sq, 2);
        float mu = sum * (1.f / 192.f);
        float rs = rsqrtf(sq * (1.f / 192.f) - mu * mu + 1e-5f);
        int rr = m / 7, ss = m - rr * 7;
        int ho = wi * 7 + rr + 3; if (ho >= 56) ho -= 56;
        int wo = wj * 7 + ss + 3; if (wo >= 56) wo -= 56;
        long tp = ((long)(bb * 56 + ho) * 56 + wo);
        #pragma unroll
        for (int i = 0; i < 6; i++) {
            bf16x8 o8, x8;
            #pragma unroll
            for (int j = 0; j < 8; j++) {
                int c = c0 + i * 8 + j;
                float xvf = vv[i * 8 + j];
                x8[j] = (short)f2bf(xvf);
                o8[j] = (short)f2bf((xvf - mu) * rs * g2[c] + b2[c]);
            }
            *(bf16x8*)(h2 + tp * 192 + c0 + i * 8) = o8;
            *(bf16x8*)(xv + tp * 192 + c0 + i * 8) = x8;
        }
    }
}

// ---------------- launcher ----------------
extern "C" void kernel_launch(void* const* d_in, const int* in_sizes, int n_in,
                              void* d_out, int out_size, void* d_ws, size_t ws_size,
                              hipStream_t stream)
{
    const float* x      = (const float*)d_in[0];
    const float* n1g    = (const float*)d_in[1];
    const float* n1b    = (const float*)d_in[2];
    const float* qkv_w  = (const float*)d_in[3];
    const float* qkv_b  = (const float*)d_in[4];
    const float* proj_w = (const float*)d_in[5];
    const float* proj_b = (const float*)d_in[6];
    const float* rpb    = (const float*)d_in[7];
    const float* pl_w   = (const float*)d_in[8];
    const float* pl_b   = (const float*)d_in[9];
    const float* pw_w   = (const float*)d_in[10];
    const float* pw_b   = (const float*)d_in[11];
    const float* n2g    = (const float*)d_in[12];
    const float* n2b    = (const float*)d_in[13];
    const float* fc1_w  = (const float*)d_in[14];
    const float* fc1_b  = (const float*)d_in[15];
    const float* fc2_w  = (const float*)d_in[16];
    const float* fc2_b  = (const float*)d_in[17];

    float* out   = (float*)d_out;   // f32: [xo | q | k | v], each OUTCH elements
    float* out_q = out + OUTCH;

    // ws: bufT (h2) 38,535,168 | xvB 38,535,168 | bufW 884,736
    char* ws = (char*)d_ws;
    unsigned short* bufT = (unsigned short*)ws;
    unsigned short* xvB  = (unsigned short*)(ws + 38535168);
    unsigned short* bufW = (unsigned short*)(ws + 2 * 38535168L);

    k_prep_w<<<1728, 256, 0, stream>>>(qkv_w, proj_w, fc1_w, fc2_w, bufW);
    k_attn<<<NWIN, 384, 0, stream>>>(x, n1g, n1b, bufW, qkv_b,
                                     rpb, pl_w, pl_b, pw_w, pw_b,
                                     bufW + 110592, proj_b, n2g, n2b,
                                     out_q, xvB, bufT);                       // q/k/v + h2 + xv
    k_mlp<<<1568, 256, 0, stream>>>(bufT, bufW + 147456, fc1_b, bufW + 294912, fc2_b,
                                    xvB, out);
}

// Round 17
// 398.736 us; speedup vs baseline: 1.0633x; 1.0633x over previous
//
#include <hip/hip_runtime.h>
#include <math.h>

// ---------------- problem constants ----------------
#define TOK   100352            // B * H * W  = 32*56*56  (= B_ * N = 2048*49)
#define OUTCH 19267584L         // TOK * 192, elements per output chunk (f32)
#define NWIN  2048

typedef __attribute__((ext_vector_type(4))) float f32x4;
typedef __attribute__((ext_vector_type(8))) short bf16x8;

__device__ __forceinline__ unsigned short f2bf(float f) {
    unsigned u = __builtin_bit_cast(unsigned, f);
    u += 0x7FFFu + ((u >> 16) & 1u);          // round-to-nearest-even
    return (unsigned short)(u >> 16);
}
__device__ __forceinline__ float bf2f(unsigned short s) {
    return __builtin_bit_cast(float, (unsigned)s << 16);
}

// ---------------- weight prep: all four weight matrices MFMA fragment-packed ----------------
// wt layout (bf16):
//  [0,110592)        qkvp6: 216 slots instr=((s*6+h)*2+ni)*6+ks  (6-wave attn kernel; s<3,h<6,ni<2)
//  [110592,147456)   projp6: 72 slots instr=((h*2+ni)*6+ks), h<6
//  [147456,294912)   w1p:  288 slots  instr=((s*4+wv)*3+ni)*6+ks, s<4
//  [294912,442368)   w2p:  288 slots  (same index, k runs over 768)
// Each slot = 512 bf16 = lane*8+j  -> wave load = coalesced 1 KB.
__global__ __launch_bounds__(256) void k_prep_w(const float* __restrict__ qkv_w,
                                                const float* __restrict__ proj_w,
                                                const float* __restrict__ fc1_w,
                                                const float* __restrict__ fc2_w,
                                                unsigned short* __restrict__ wt)
{
    int i = blockIdx.x * 256 + threadIdx.x;   // grid covers exactly 442368
    float v;
    if (i < 110592) {
        int instr = i >> 9, rem = i & 511, lane = rem >> 3, j = rem & 7;
        int ks = instr % 6, t = instr / 6;
        int ni = t & 1, t2 = t >> 1;                         // t2 = s*6+h in [0,18)
        int hh = t2 % 6, s = t2 / 6;
        int n = s * 192 + hh * 32 + ni * 16 + (lane & 15);   // out col in [0,576)
        int k = ks * 32 + ((lane >> 4) << 3) + j;            // k in [0,192)
        v = qkv_w[k * 576 + n];
    } else if (i < 147456) {
        int j2 = i - 110592;
        int instr = j2 >> 9, rem = j2 & 511, lane = rem >> 3, j = rem & 7;
        int ks = instr % 6, t = instr / 6;                   // t in [0,12)
        int ni = t & 1, hh = t >> 1;                         // ni<2, head hh<6
        int n = hh * 32 + ni * 16 + (lane & 15);             // out col in [0,192)
        int k = ks * 32 + ((lane >> 4) << 3) + j;
        v = proj_w[k * 192 + n];
    } else if (i < 294912) {
        int j2 = i - 147456;
        int instr = j2 >> 9, rem = j2 & 511, lane = rem >> 3, j = rem & 7;
        int ks = instr % 6, t = instr / 6;
        int ni = t % 3, t2 = t / 3;
        int wv = t2 & 3, s = t2 >> 2;
        int n = s * 192 + wv * 48 + ni * 16 + (lane & 15);   // fc1 out col in [0,768)
        int k = ks * 32 + ((lane >> 4) << 3) + j;            // k in [0,192)
        v = fc1_w[k * 768 + n];
    } else {
        int j2 = i - 294912;
        int instr = j2 >> 9, rem = j2 & 511, lane = rem >> 3, j = rem & 7;
        int ks = instr % 6, t = instr / 6;
        int ni = t % 3, t2 = t / 3;
        int wv = t2 & 3, s = t2 >> 2;
        int n = wv * 48 + ni * 16 + (lane & 15);             // fc2 out col in [0,192)
        int k = s * 192 + ks * 32 + ((lane >> 4) << 3) + j;  // hidden in [0,768)
        v = fc2_w[k * 192 + n];
    }
    wt[i] = f2bf(v);
}

// ---------------- fused MLP: xo = xv + fc2(gelu(fc1(h2))) + b2 (single write) ----------------
__global__ __launch_bounds__(256) void k_mlp(const unsigned short* __restrict__ h2,
                                             const unsigned short* __restrict__ w1p,
                                             const float* __restrict__ b1,
                                             const unsigned short* __restrict__ w2p,
                                             const float* __restrict__ b2,
                                             const unsigned short* __restrict__ xv,
                                             float* __restrict__ xo)
{
    __shared__ unsigned short lA[64 * 192];   // h2 tile, swizzled
    __shared__ unsigned short lH[64 * 192];   // gelu(fc1) slab, swizzled
    const int tid = threadIdx.x, lane = tid & 63, wv = tid >> 6;
    const long m0 = (long)blockIdx.x * 64;

    #pragma unroll
    for (int c = tid; c < 64 * 24; c += 256) {
        int row = c / 24, k16 = c - row * 24;
        bf16x8 v = *(const bf16x8*)(h2 + (m0 + row) * 192 + k16 * 8);
        *(bf16x8*)((char*)lA + row * 384 + ((k16 * 16) ^ ((row & 7) << 4))) = v;
    }

    f32x4 acc2[4][3];
    #pragma unroll
    for (int mi = 0; mi < 4; mi++)
        #pragma unroll
        for (int ni = 0; ni < 3; ni++) acc2[mi][ni] = (f32x4){0.f, 0.f, 0.f, 0.f};
    __syncthreads();

    for (int s = 0; s < 4; s++) {
        f32x4 acc1[4][3];
        #pragma unroll
        for (int mi = 0; mi < 4; mi++)
            #pragma unroll
            for (int ni = 0; ni < 3; ni++) acc1[mi][ni] = (f32x4){0.f, 0.f, 0.f, 0.f};
        #pragma unroll
        for (int ks = 0; ks < 6; ks++) {
            int kb = ks * 64 + ((lane >> 4) << 4);
            bf16x8 bfr[3];
            #pragma unroll
            for (int ni = 0; ni < 3; ni++) {
                int instr = ((s * 4 + wv) * 3 + ni) * 6 + ks;
                bfr[ni] = *(const bf16x8*)(w1p + (instr << 9) + (lane << 3));
            }
            #pragma unroll
            for (int mi = 0; mi < 4; mi++) {
                int row = mi * 16 + (lane & 15);
                bf16x8 afr = *(const bf16x8*)((char*)lA + row * 384 + (kb ^ ((row & 7) << 4)));
                #pragma unroll
                for (int ni = 0; ni < 3; ni++)
                    acc1[mi][ni] = __builtin_amdgcn_mfma_f32_16x16x32_bf16(afr, bfr[ni], acc1[mi][ni], 0, 0, 0);
            }
        }
        __syncthreads();     // previous slab's GEMM2 reads of lH are done
        #pragma unroll
        for (int mi = 0; mi < 4; mi++)
            #pragma unroll
            for (int ni = 0; ni < 3; ni++) {
                int col = wv * 48 + ni * 16 + (lane & 15);
                float bv = b1[s * 192 + col];
                #pragma unroll
                for (int r = 0; r < 4; r++) {
                    int row = mi * 16 + ((lane >> 4) << 2) + r;
                    float v = acc1[mi][ni][r] + bv;
                    float ge = 0.5f * v * (1.f + erff(v * 0.70710678118654752f));
                    *(unsigned short*)((char*)lH + row * 384 + ((2 * col) ^ ((row & 7) << 4))) = f2bf(ge);
                }
            }
        __syncthreads();
        #pragma unroll
        for (int ks = 0; ks < 6; ks++) {
            int kb = ks * 64 + ((lane >> 4) << 4);
            bf16x8 bfr[3];
            #pragma unroll
            for (int ni = 0; ni < 3; ni++) {
                int instr = ((s * 4 + wv) * 3 + ni) * 6 + ks;
                bfr[ni] = *(const bf16x8*)(w2p + (instr << 9) + (lane << 3));
            }
            #pragma unroll
            for (int mi = 0; mi < 4; mi++) {
                int row = mi * 16 + (lane & 15);
                bf16x8 afr = *(const bf16x8*)((char*)lH + row * 384 + (kb ^ ((row & 7) << 4)));
                #pragma unroll
                for (int ni = 0; ni < 3; ni++)
                    acc2[mi][ni] = __builtin_amdgcn_mfma_f32_16x16x32_bf16(afr, bfr[ni], acc2[mi][ni], 0, 0, 0);
            }
        }
    }
    #pragma unroll
    for (int mi = 0; mi < 4; mi++)
        #pragma unroll
        for (int ni = 0; ni < 3; ni++) {
            int gcol = wv * 48 + ni * 16 + (lane & 15);
            float bv = b2[gcol];
            #pragma unroll
            for (int r = 0; r < 4; r++) {
                long grow = m0 + mi * 16 + ((lane >> 4) << 2) + r;
                xo[grow * 192 + gcol] = bf2f(xv[grow * 192 + gcol]) + acc2[mi][ni][r] + bv;
            }
        }
}

// ---------------- mega-fused: LN1 + QKV + attention + proj + LN2 ----------------
// One block (6 waves = 6 heads) per window. LDS map (136,240 B, 1 block/CU):
//   [0, 78800)        phase A: lA (LN1'd input, 18.8 KB, swizzled) then ATT f32 [6][49][67]
//                     phase C: PO (18.8 KB swizzled) + xoT f32 [49][196] at +19200
//   [78800, 97616)    qL bf16 49x192 swizzled (384 B rows)
//   [97616, 116432)   kL bf16 49x192 swizzled
//   [116432, 136228)  vL bf16 49 rows x 404 B stride (unswizzled)
#define ATS 67
#define QL_OFF 78800
#define KL_OFF 97616
#define VL_OFF 116432
__global__ __launch_bounds__(384) void k_attn(const float* __restrict__ x,
                                              const float* __restrict__ n1g,
                                              const float* __restrict__ n1b,
                                              const unsigned short* __restrict__ qkvp,
                                              const float* __restrict__ qbias,
                                              const float* __restrict__ rpb,
                                              const float* __restrict__ plw,
                                              const float* __restrict__ plb,
                                              const float* __restrict__ pww,
                                              const float* __restrict__ pwb,
                                              const unsigned short* __restrict__ projp,
                                              const float* __restrict__ pbias,
                                              const float* __restrict__ g2,
                                              const float* __restrict__ b2,
                                              float* __restrict__ outq,           // q chunk; k,v at +OUTCH,+2*OUTCH
                                              unsigned short* __restrict__ xv,
                                              unsigned short* __restrict__ h2)
{
    __shared__ __align__(16) char SM[136240];
    float (*ATT)[49][ATS] = (float(*)[49][ATS])SM;
    float (*xoT)[196]     = (float(*)[196])(SM + 19200);

    int w = blockIdx.x, widx = w & 63;
    int tid = threadIdx.x, lane = tid & 63, h = tid >> 6;   // wave id == head
    int wi = widx >> 3, wj = widx & 7, bb = w >> 6;
    const long rowbase = (long)w * 49;
    const bool bdry = (wi == 7) || (wj == 7);

    // ---- Phase 1: LN1 + roll(-3,-3) gather -> lA (rows 0..48, swizzled) ----
    if (tid < 196) {
        int r = tid >> 2, c0 = (tid & 3) * 48;
        int rr = r / 7, ss = r - rr * 7;
        int hh = wi * 7 + rr + 3; if (hh >= 56) hh -= 56;
        int ww = wj * 7 + ss + 3; if (ww >= 56) ww -= 56;
        const f32x4* sp = (const f32x4*)(x + ((long)(bb * 56 + hh) * 56 + ww) * 192 + c0);
        f32x4 vv[12];
        float sum = 0.f, sq = 0.f;
        #pragma unroll
        for (int i = 0; i < 12; i++) {
            vv[i] = sp[i];
            #pragma unroll
            for (int j = 0; j < 4; j++) { sum += vv[i][j]; sq += vv[i][j] * vv[i][j]; }
        }
        sum += __shfl_xor(sum, 1); sq += __shfl_xor(sq, 1);
        sum += __shfl_xor(sum, 2); sq += __shfl_xor(sq, 2);
        float mu = sum * (1.f / 192.f);
        float rs = rsqrtf(sq * (1.f / 192.f) - mu * mu + 1e-5f);
        #pragma unroll
        for (int i = 0; i < 6; i++) {
            bf16x8 o8;
            #pragma unroll
            for (int j = 0; j < 8; j++) {
                int idx = i * 8 + j, c = c0 + idx;
                o8[j] = (short)f2bf((vv[idx >> 2][idx & 3] - mu) * rs * n1g[c] + n1b[c]);
            }
            *(bf16x8*)(SM + r * 384 + ((2 * (c0 + i * 8)) ^ ((r & 7) << 4))) = o8;
        }
    }
    __syncthreads();

    // ---- Phase 2: QKV GEMM; wave h computes head h's 32 cols of q,k,v ----
    f32x4 aq[4][2], ak[4][2], av[4][2];
    #pragma unroll
    for (int mi = 0; mi < 4; mi++)
        #pragma unroll
        for (int ni = 0; ni < 2; ni++) {
            aq[mi][ni] = (f32x4){0.f, 0.f, 0.f, 0.f};
            ak[mi][ni] = (f32x4){0.f, 0.f, 0.f, 0.f};
            av[mi][ni] = (f32x4){0.f, 0.f, 0.f, 0.f};
        }
    #pragma unroll
    for (int ks = 0; ks < 6; ks++) {
        int kb = ks * 64 + ((lane >> 4) << 4);
        bf16x8 afr[4];
        #pragma unroll
        for (int mi = 0; mi < 4; mi++) {
            int row = mi * 16 + (lane & 15);                 // rows 49..63 read garbage (outputs discarded)
            afr[mi] = *(const bf16x8*)(SM + row * 384 + (kb ^ ((row & 7) << 4)));
        }
        bf16x8 bq[2], bk[2], bv[2];
        #pragma unroll
        for (int ni = 0; ni < 2; ni++) {
            bq[ni] = *(const bf16x8*)(qkvp + (((((0 * 6 + h) * 2 + ni) * 6 + ks)) << 9) + (lane << 3));
            bk[ni] = *(const bf16x8*)(qkvp + (((((1 * 6 + h) * 2 + ni) * 6 + ks)) << 9) + (lane << 3));
            bv[ni] = *(const bf16x8*)(qkvp + (((((2 * 6 + h) * 2 + ni) * 6 + ks)) << 9) + (lane << 3));
        }
        #pragma unroll
        for (int mi = 0; mi < 4; mi++)
            #pragma unroll
            for (int ni = 0; ni < 2; ni++) {
                aq[mi][ni] = __builtin_amdgcn_mfma_f32_16x16x32_bf16(afr[mi], bq[ni], aq[mi][ni], 0, 0, 0);
                ak[mi][ni] = __builtin_amdgcn_mfma_f32_16x16x32_bf16(afr[mi], bk[ni], ak[mi][ni], 0, 0, 0);
                av[mi][ni] = __builtin_amdgcn_mfma_f32_16x16x32_bf16(afr[mi], bv[ni], av[mi][ni], 0, 0, 0);
            }
    }
    // epilogue: d_out f32 (required outputs) + bf16 LDS copies
    #pragma unroll
    for (int mi = 0; mi < 4; mi++)
        #pragma unroll
        for (int ni = 0; ni < 2; ni++) {
            int col = h * 32 + ni * 16 + (lane & 15);
            float bgq = qbias[col], bgk = qbias[192 + col], bgv = qbias[384 + col];
            #pragma unroll
            for (int r = 0; r < 4; r++) {
                int m = mi * 16 + ((lane >> 4) << 2) + r;
                if (m < 49) {
                    long gr = (rowbase + m) * 192 + col;
                    float fq = aq[mi][ni][r] + bgq;
                    float fk = ak[mi][ni][r] + bgk;
                    float fv = av[mi][ni][r] + bgv;
                    outq[gr] = fq; outq[OUTCH + gr] = fk; outq[2 * OUTCH + gr] = fv;
                    int sw = (2 * col) ^ ((m & 7) << 4);
                    *(unsigned short*)(SM + QL_OFF + m * 384 + sw) = f2bf(fq);
                    *(unsigned short*)(SM + KL_OFF + m * 384 + sw) = f2bf(fk);
                    *(unsigned short*)(SM + VL_OFF + m * 404 + 2 * col) = f2bf(fv);
                }
            }
        }
    __syncthreads();

    // ---- Phase 3: zero ATT pad cols [49,64) (lA dead; ATT region fresh) ----
    for (int c = tid; c < 6 * 49 * 15; c += 384) {
        int g = c / (49 * 15), rem = c - g * (49 * 15);
        int m = rem / 15, n = 49 + (rem - m * 15);
        ATT[g][m][n] = 0.f;
    }

    // ---- Phase 4: QK^T from qL/kL (b128 swizzled fragment reads) ----
    bf16x8 qfr[4], kfr[4];
    #pragma unroll
    for (int mi = 0; mi < 4; mi++) {
        int m = mi * 16 + (lane & 15); if (m > 48) m = 48;
        qfr[mi] = *(const bf16x8*)(SM + QL_OFF + m * 384 + ((h * 64 + ((lane >> 4) << 4)) ^ ((m & 7) << 4)));
    }
    #pragma unroll
    for (int ni = 0; ni < 4; ni++) {
        int n = ni * 16 + (lane & 15); if (n > 48) n = 48;
        kfr[ni] = *(const bf16x8*)(SM + KL_OFF + n * 384 + ((h * 64 + ((lane >> 4) << 4)) ^ ((n & 7) << 4)));
    }
    f32x4 sa[4][4];
    #pragma unroll
    for (int ni = 0; ni < 4; ni++)
        #pragma unroll
        for (int mi = 0; mi < 4; mi++)
            sa[mi][ni] = __builtin_amdgcn_mfma_f32_16x16x32_bf16(qfr[mi], kfr[ni], (f32x4){0.f, 0.f, 0.f, 0.f}, 0, 0, 0);
    const float scale = 0.17677669529663687f;   // 32^-0.5
    #pragma unroll
    for (int mi = 0; mi < 4; mi++)
        #pragma unroll
        for (int ni = 0; ni < 4; ni++)
            #pragma unroll
            for (int r = 0; r < 4; r++) {
                int m = mi * 16 + ((lane >> 4) << 2) + r, n = ni * 16 + (lane & 15);
                if (m < 49 && n < 49) {
                    int rq = m / 7, cq = m - rq * 7, rk = n / 7, ck = n - rk * 7;
                    int ridx = (rq - rk + 6) * 13 + (cq - ck + 6);
                    ATT[h][m][n] = sa[mi][ni][r] * scale + rpb[ridx * 6 + h];
                }
            }
    __syncthreads();

    // ---- Phase 5: pl head-mix + shift mask (in place; interior windows skip mask) ----
    for (int p = tid; p < 2401; p += 384) {
        int m = p / 49, n = p - m * 49;
        float a[6];
        #pragma unroll
        for (int g = 0; g < 6; g++) a[g] = ATT[g][m][n];
        float msk = 0.f;
        if (bdry) {
            int rq = m / 7, cq = m - rq * 7, rk = n / 7, ck = n - rk * 7;
            int ghq = wi * 7 + rq, gwq = wj * 7 + cq, ghk = wi * 7 + rk, gwk = wj * 7 + ck;
            int regq = (ghq < 49 ? 0 : (ghq < 53 ? 1 : 2)) * 3 + (gwq < 49 ? 0 : (gwq < 53 ? 1 : 2));
            int regk = (ghk < 49 ? 0 : (ghk < 53 ? 1 : 2)) * 3 + (gwk < 49 ? 0 : (gwk < 53 ? 1 : 2));
            msk = (regq != regk) ? -100.f : 0.f;
        }
        #pragma unroll
        for (int g = 0; g < 6; g++) {
            float v = plb[g] + msk;
            #pragma unroll
            for (int h2i = 0; h2i < 6; h2i++) v += a[h2i] * plw[h2i * 6 + g];
            ATT[g][m][n] = v;
        }
    }
    __syncthreads();

    // ---- Phase 6: softmax, row-per-lane ----
    if (tid < 294) {
        int g = tid / 49, m = tid - g * 49;
        float* row = &ATT[g][m][0];
        float mx = row[0];
        #pragma unroll
        for (int j = 1; j < 49; j++) mx = fmaxf(mx, row[j]);
        float e[49]; float sm = 0.f;
        #pragma unroll
        for (int j = 0; j < 49; j++) { e[j] = __expf(row[j] - mx); sm += e[j]; }
        float inv = 1.f / sm;
        #pragma unroll
        for (int j = 0; j < 49; j++) row[j] = e[j] * inv;
    }
    __syncthreads();

    // ---- Phase 7: pw head-mix (in place) ----
    for (int p = tid; p < 2401; p += 384) {
        int m = p / 49, n = p - m * 49;
        float a[6];
        #pragma unroll
        for (int g = 0; g < 6; g++) a[g] = ATT[g][m][n];
        #pragma unroll
        for (int g = 0; g < 6; g++) {
            float v = pwb[g];
            #pragma unroll
            for (int h2i = 0; h2i < 6; h2i++) v += a[h2i] * pww[h2i * 6 + g];
            ATT[g][m][n] = v;
        }
    }
    __syncthreads();

    // ---- Phase 8: PV (P-frags from ATT, V-frags from vL) ----
    bf16x8 vfr[2][2];
    #pragma unroll
    for (int kst = 0; kst < 2; kst++)
        #pragma unroll
        for (int ni = 0; ni < 2; ni++) {
            int d = h * 32 + ni * 16 + (lane & 15);
            #pragma unroll
            for (int j = 0; j < 8; j++) {
                int n = kst * 32 + ((lane >> 4) << 3) + j; if (n > 48) n = 48;
                vfr[kst][ni][j] = *(const unsigned short*)(SM + VL_OFF + n * 404 + 2 * d);
            }
        }
    f32x4 oa[4][2];
    #pragma unroll
    for (int mi = 0; mi < 4; mi++)
        #pragma unroll
        for (int ni = 0; ni < 2; ni++) oa[mi][ni] = (f32x4){0.f, 0.f, 0.f, 0.f};
    #pragma unroll
    for (int kst = 0; kst < 2; kst++) {
        #pragma unroll
        for (int mi = 0; mi < 4; mi++) {
            int m = mi * 16 + (lane & 15); if (m > 48) m = 48;
            const float* ap = &ATT[h][m][kst * 32 + ((lane >> 4) << 3)];
            bf16x8 afr;
            #pragma unroll
            for (int j = 0; j < 8; j++) afr[j] = (short)f2bf(ap[j]);
            #pragma unroll
            for (int ni = 0; ni < 2; ni++)
                oa[mi][ni] = __builtin_amdgcn_mfma_f32_16x16x32_bf16(afr, vfr[kst][ni], oa[mi][ni], 0, 0, 0);
        }
    }
    __syncthreads();                         // all ATT reads done; region reusable

    // ---- Phase 9: PV-out -> PO (bf16, swizzled) in dead ATT space ----
    #pragma unroll
    for (int mi = 0; mi < 4; mi++)
        #pragma unroll
        for (int ni = 0; ni < 2; ni++)
            #pragma unroll
            for (int r = 0; r < 4; r++) {
                int m = mi * 16 + ((lane >> 4) << 2) + r;
                if (m < 49) {
                    int col = h * 32 + ni * 16 + (lane & 15);
                    *(unsigned short*)(SM + m * 384 + ((2 * col) ^ ((m & 7) << 4))) = f2bf(oa[mi][ni][r]);
                }
            }
    __syncthreads();

    // ---- Phase 10: proj GEMM (wave h -> cols h*32..+32) ----
    f32x4 pacc[4][2];
    #pragma unroll
    for (int mi = 0; mi < 4; mi++)
        #pragma unroll
        for (int ni = 0; ni < 2; ni++) pacc[mi][ni] = (f32x4){0.f, 0.f, 0.f, 0.f};
    #pragma unroll
    for (int ks = 0; ks < 6; ks++) {
        int kb = ks * 64 + ((lane >> 4) << 4);
        bf16x8 bfr[2];
        #pragma unroll
        for (int ni = 0; ni < 2; ni++) {
            int instr = (h * 2 + ni) * 6 + ks;
            bfr[ni] = *(const bf16x8*)(projp + (instr << 9) + (lane << 3));
        }
        #pragma unroll
        for (int mi = 0; mi < 4; mi++) {
            int row = mi * 16 + (lane & 15); if (row > 48) row = 48;
            bf16x8 afr = *(const bf16x8*)(SM + row * 384 + (kb ^ ((row & 7) << 4)));
            #pragma unroll
            for (int ni = 0; ni < 2; ni++)
                pacc[mi][ni] = __builtin_amdgcn_mfma_f32_16x16x32_bf16(afr, bfr[ni], pacc[mi][ni], 0, 0, 0);
        }
    }

    // ---- Phase 11: residual gather xoT[m][gc] = x[spatial] + proj + pbias ----
    #pragma unroll
    for (int mi = 0; mi < 4; mi++)
        #pragma unroll
        for (int ni = 0; ni < 2; ni++) {
            int gc = h * 32 + ni * 16 + (lane & 15);
            float bv = pbias[gc];
            #pragma unroll
            for (int r = 0; r < 4; r++) {
                int m = mi * 16 + ((lane >> 4) << 2) + r;
                if (m < 49) {
                    int rr = m / 7, ss = m - rr * 7;
                    int ho = wi * 7 + rr + 3; if (ho >= 56) ho -= 56;     // roll(+SHIFT)
                    int wo = wj * 7 + ss + 3; if (wo >= 56) wo -= 56;
                    long tp = ((long)(bb * 56 + ho) * 56 + wo);
                    xoT[m][gc] = x[tp * 192 + gc] + pacc[mi][ni][r] + bv;
                }
            }
        }
    __syncthreads();

    // ---- Phase 12: LN2 + spatial writes of h2 and xv (bf16) ----
    if (tid < 196) {
        int m = tid >> 2, c0 = (tid & 3) * 48;
        float vv[48];
        float sum = 0.f, sq = 0.f;
        #pragma unroll
        for (int i = 0; i < 48; i++) { vv[i] = xoT[m][c0 + i]; sum += vv[i]; sq += vv[i] * vv[i]; }
        sum += __shfl_xor(sum, 1); sq += __shfl_xor(sq, 1);
        sum += __shfl_xor(sum, 2); sq += __shfl_xor(sq, 2);
        float mu = sum * (1.f / 192.f);
        float rs = rsqrtf(sq * (1.f / 192.f) - mu * mu + 1e-5f);
        int rr = m / 7, ss = m - rr * 7;
        int ho = wi * 7 + rr + 3; if (ho >= 56) ho -= 56;
        int wo = wj * 7 + ss + 3; if (wo >= 56) wo -= 56;
        long tp = ((long)(bb * 56 + ho) * 56 + wo);
        #pragma unroll
        for (int i = 0; i < 6; i++) {
            bf16x8 o8, x8;
            #pragma unroll
            for (int j = 0; j < 8; j++) {
                int c = c0 + i * 8 + j;
                float xvf = vv[i * 8 + j];
                x8[j] = (short)f2bf(xvf);
                o8[j] = (short)f2bf((xvf - mu) * rs * g2[c] + b2[c]);
            }
            *(bf16x8*)(h2 + tp * 192 + c0 + i * 8) = o8;
            *(bf16x8*)(xv + tp * 192 + c0 + i * 8) = x8;
        }
    }
}

// ---------------- launcher ----------------
extern "C" void kernel_launch(void* const* d_in, const int* in_sizes, int n_in,
                              void* d_out, int out_size, void* d_ws, size_t ws_size,
                              hipStream_t stream)
{
    const float* x      = (const float*)d_in[0];
    const float* n1g    = (const float*)d_in[1];
    const float* n1b    = (const float*)d_in[2];
    const float* qkv_w  = (const float*)d_in[3];
    const float* qkv_b  = (const float*)d_in[4];
    const float* proj_w = (const float*)d_in[5];
    const float* proj_b = (const float*)d_in[6];
    const float* rpb    = (const float*)d_in[7];
    const float* pl_w   = (const float*)d_in[8];
    const float* pl_b   = (const float*)d_in[9];
    const float* pw_w   = (const float*)d_in[10];
    const float* pw_b   = (const float*)d_in[11];
    const float* n2g    = (const float*)d_in[12];
    const float* n2b    = (const float*)d_in[13];
    const float* fc1_w  = (const float*)d_in[14];
    const float* fc1_b  = (const float*)d_in[15];
    const float* fc2_w  = (const float*)d_in[16];
    const float* fc2_b  = (const float*)d_in[17];

    float* out   = (float*)d_out;   // f32: [xo | q | k | v], each OUTCH elements
    float* out_q = out + OUTCH;

    // ws: bufT (h2) 38,535,168 | xvB 38,535,168 | bufW 884,736
    char* ws = (char*)d_ws;
    unsigned short* bufT = (unsigned short*)ws;
    unsigned short* xvB  = (unsigned short*)(ws + 38535168);
    unsigned short* bufW = (unsigned short*)(ws + 2 * 38535168L);

    k_prep_w<<<1728, 256, 0, stream>>>(qkv_w, proj_w, fc1_w, fc2_w, bufW);
    k_attn<<<NWIN, 384, 0, stream>>>(x, n1g, n1b, bufW, qkv_b,
                                     rpb, pl_w, pl_b, pw_w, pw_b,
                                     bufW + 110592, proj_b, n2g, n2b,
                                     out_q, xvB, bufT);                       // q/k/v + h2 + xv
    k_mlp<<<1568, 256, 0, stream>>>(bufT, bufW + 147456, fc1_b, bufW + 294912, fc2_b,
                                    xvB, out);
}

// Round 18
// 389.771 us; speedup vs baseline: 1.0878x; 1.0230x over previous
//
#include <hip/hip_runtime.h>
#include <math.h>

// ---------------- problem constants ----------------
#define TOK   100352            // B * H * W  = 32*56*56  (= B_ * N = 2048*49)
#define OUTCH 19267584L         // TOK * 192, elements per output chunk (f32)
#define NWIN  2048

typedef __attribute__((ext_vector_type(4))) float f32x4;
typedef __attribute__((ext_vector_type(8))) short bf16x8;

__device__ __forceinline__ unsigned short f2bf(float f) {
    unsigned u = __builtin_bit_cast(unsigned, f);
    u += 0x7FFFu + ((u >> 16) & 1u);          // round-to-nearest-even
    return (unsigned short)(u >> 16);
}
__device__ __forceinline__ float bf2f(unsigned short s) {
    return __builtin_bit_cast(float, (unsigned)s << 16);
}

// ---------------- weight prep: all four weight matrices MFMA fragment-packed ----------------
// wt layout (bf16):
//  [0,110592)        qkvp6: 216 slots instr=((s*6+h)*2+ni)*6+ks  (6-wave attn kernel; s<3,h<6,ni<2)
//  [110592,147456)   projp6: 72 slots instr=((h*2+ni)*6+ks), h<6
//  [147456,294912)   w1p:  288 slots  instr=((s*4+wv)*3+ni)*6+ks, s<4
//  [294912,442368)   w2p:  288 slots  (same index, k runs over 768)
// Each slot = 512 bf16 = lane*8+j  -> wave load = coalesced 1 KB.
__global__ __launch_bounds__(256) void k_prep_w(const float* __restrict__ qkv_w,
                                                const float* __restrict__ proj_w,
                                                const float* __restrict__ fc1_w,
                                                const float* __restrict__ fc2_w,
                                                unsigned short* __restrict__ wt)
{
    int i = blockIdx.x * 256 + threadIdx.x;   // grid covers exactly 442368
    float v;
    if (i < 110592) {
        int instr = i >> 9, rem = i & 511, lane = rem >> 3, j = rem & 7;
        int ks = instr % 6, t = instr / 6;
        int ni = t & 1, t2 = t >> 1;                         // t2 = s*6+h in [0,18)
        int hh = t2 % 6, s = t2 / 6;
        int n = s * 192 + hh * 32 + ni * 16 + (lane & 15);   // out col in [0,576)
        int k = ks * 32 + ((lane >> 4) << 3) + j;            // k in [0,192)
        v = qkv_w[k * 576 + n];
    } else if (i < 147456) {
        int j2 = i - 110592;
        int instr = j2 >> 9, rem = j2 & 511, lane = rem >> 3, j = rem & 7;
        int ks = instr % 6, t = instr / 6;                   // t in [0,12)
        int ni = t & 1, hh = t >> 1;                         // ni<2, head hh<6
        int n = hh * 32 + ni * 16 + (lane & 15);             // out col in [0,192)
        int k = ks * 32 + ((lane >> 4) << 3) + j;
        v = proj_w[k * 192 + n];
    } else if (i < 294912) {
        int j2 = i - 147456;
        int instr = j2 >> 9, rem = j2 & 511, lane = rem >> 3, j = rem & 7;
        int ks = instr % 6, t = instr / 6;
        int ni = t % 3, t2 = t / 3;
        int wv = t2 & 3, s = t2 >> 2;
        int n = s * 192 + wv * 48 + ni * 16 + (lane & 15);   // fc1 out col in [0,768)
        int k = ks * 32 + ((lane >> 4) << 3) + j;            // k in [0,192)
        v = fc1_w[k * 768 + n];
    } else {
        int j2 = i - 294912;
        int instr = j2 >> 9, rem = j2 & 511, lane = rem >> 3, j = rem & 7;
        int ks = instr % 6, t = instr / 6;
        int ni = t % 3, t2 = t / 3;
        int wv = t2 & 3, s = t2 >> 2;
        int n = wv * 48 + ni * 16 + (lane & 15);             // fc2 out col in [0,192)
        int k = s * 192 + ks * 32 + ((lane >> 4) << 3) + j;  // hidden in [0,768)
        v = fc2_w[k * 192 + n];
    }
    wt[i] = f2bf(v);
}

// ---------------- fused MLP: xo = xv + fc2(gelu(fc1(h2))) + b2 (single write) ----------------
__global__ __launch_bounds__(256) void k_mlp(const unsigned short* __restrict__ h2,
                                             const unsigned short* __restrict__ w1p,
                                             const float* __restrict__ b1,
                                             const unsigned short* __restrict__ w2p,
                                             const float* __restrict__ b2,
                                             const unsigned short* __restrict__ xv,
                                             float* __restrict__ xo)
{
    __shared__ unsigned short lA[64 * 192];   // h2 tile, swizzled
    __shared__ unsigned short lH[64 * 192];   // gelu(fc1) slab, swizzled
    const int tid = threadIdx.x, lane = tid & 63, wv = tid >> 6;
    const long m0 = (long)blockIdx.x * 64;

    #pragma unroll
    for (int c = tid; c < 64 * 24; c += 256) {
        int row = c / 24, k16 = c - row * 24;
        bf16x8 v = *(const bf16x8*)(h2 + (m0 + row) * 192 + k16 * 8);
        *(bf16x8*)((char*)lA + row * 384 + ((k16 * 16) ^ ((row & 7) << 4))) = v;
    }

    f32x4 acc2[4][3];
    #pragma unroll
    for (int mi = 0; mi < 4; mi++)
        #pragma unroll
        for (int ni = 0; ni < 3; ni++) acc2[mi][ni] = (f32x4){0.f, 0.f, 0.f, 0.f};
    __syncthreads();

    for (int s = 0; s < 4; s++) {
        f32x4 acc1[4][3];
        #pragma unroll
        for (int mi = 0; mi < 4; mi++)
            #pragma unroll
            for (int ni = 0; ni < 3; ni++) acc1[mi][ni] = (f32x4){0.f, 0.f, 0.f, 0.f};
        #pragma unroll
        for (int ks = 0; ks < 6; ks++) {
            int kb = ks * 64 + ((lane >> 4) << 4);
            bf16x8 bfr[3];
            #pragma unroll
            for (int ni = 0; ni < 3; ni++) {
                int instr = ((s * 4 + wv) * 3 + ni) * 6 + ks;
                bfr[ni] = *(const bf16x8*)(w1p + (instr << 9) + (lane << 3));
            }
            #pragma unroll
            for (int mi = 0; mi < 4; mi++) {
                int row = mi * 16 + (lane & 15);
                bf16x8 afr = *(const bf16x8*)((char*)lA + row * 384 + (kb ^ ((row & 7) << 4)));
                #pragma unroll
                for (int ni = 0; ni < 3; ni++)
                    acc1[mi][ni] = __builtin_amdgcn_mfma_f32_16x16x32_bf16(afr, bfr[ni], acc1[mi][ni], 0, 0, 0);
            }
        }
        __syncthreads();     // previous slab's GEMM2 reads of lH are done
        #pragma unroll
        for (int mi = 0; mi < 4; mi++)
            #pragma unroll
            for (int ni = 0; ni < 3; ni++) {
                int col = wv * 48 + ni * 16 + (lane & 15);
                float bv = b1[s * 192 + col];
                #pragma unroll
                for (int r = 0; r < 4; r++) {
                    int row = mi * 16 + ((lane >> 4) << 2) + r;
                    float v = acc1[mi][ni][r] + bv;
                    float ge = 0.5f * v * (1.f + erff(v * 0.70710678118654752f));
                    *(unsigned short*)((char*)lH + row * 384 + ((2 * col) ^ ((row & 7) << 4))) = f2bf(ge);
                }
            }
        __syncthreads();
        #pragma unroll
        for (int ks = 0; ks < 6; ks++) {
            int kb = ks * 64 + ((lane >> 4) << 4);
            bf16x8 bfr[3];
            #pragma unroll
            for (int ni = 0; ni < 3; ni++) {
                int instr = ((s * 4 + wv) * 3 + ni) * 6 + ks;
                bfr[ni] = *(const bf16x8*)(w2p + (instr << 9) + (lane << 3));
            }
            #pragma unroll
            for (int mi = 0; mi < 4; mi++) {
                int row = mi * 16 + (lane & 15);
                bf16x8 afr = *(const bf16x8*)((char*)lH + row * 384 + (kb ^ ((row & 7) << 4)));
                #pragma unroll
                for (int ni = 0; ni < 3; ni++)
                    acc2[mi][ni] = __builtin_amdgcn_mfma_f32_16x16x32_bf16(afr, bfr[ni], acc2[mi][ni], 0, 0, 0);
            }
        }
    }
    #pragma unroll
    for (int mi = 0; mi < 4; mi++)
        #pragma unroll
        for (int ni = 0; ni < 3; ni++) {
            int gcol = wv * 48 + ni * 16 + (lane & 15);
            float bv = b2[gcol];
            #pragma unroll
            for (int r = 0; r < 4; r++) {
                long grow = m0 + mi * 16 + ((lane >> 4) << 2) + r;
                xo[grow * 192 + gcol] = bf2f(xv[grow * 192 + gcol]) + acc2[mi][ni][r] + bv;
            }
        }
}

// ---------------- mega-fused x2: LN1 + QKV + attention + proj + LN2, TWO windows/block ----------
// 768 threads = 12 waves. Waves 0-5 -> window 2b, waves 6-11 -> window 2b+1.
// Per-window LDS region 62,144 B (x2 = 124,288 B), time-multiplexed exactly as R14:
//   [0,18816)     qL (swizzled) -> ATT bf16 [6][49][72] (after reg-staged QK^T) -> PO
//   [18816,37632) kL (swizzled) -> ATT cont. ; xoT f32 [49][196] at [18944,57360)
//   [37632,42336) ATT tail
//   [42336,62132) vL bf16 49 rows x 404 B stride (dead after PV; xoT overlaps)
#define ATS2 72
#define KL_OFF 18816
#define VL_OFF 42336
#define XOT_OFF 18944
#define WREG 62144
__global__ __launch_bounds__(768) void k_attn(const float* __restrict__ x,
                                              const float* __restrict__ n1g,
                                              const float* __restrict__ n1b,
                                              const unsigned short* __restrict__ qkvp,
                                              const float* __restrict__ qbias,
                                              const float* __restrict__ rpb,
                                              const float* __restrict__ plw,
                                              const float* __restrict__ plb,
                                              const float* __restrict__ pww,
                                              const float* __restrict__ pwb,
                                              const unsigned short* __restrict__ projp,
                                              const float* __restrict__ pbias,
                                              const float* __restrict__ g2,
                                              const float* __restrict__ b2,
                                              float* __restrict__ outq,           // q chunk; k,v at +OUTCH,+2*OUTCH
                                              unsigned short* __restrict__ xv,
                                              unsigned short* __restrict__ h2)
{
    __shared__ __align__(16) char SM[2 * WREG];

    int tid = threadIdx.x;
    int wsel = tid >= 384;
    int tid2 = tid - (wsel << 8) - (wsel << 7);             // tid - wsel*384
    int lane = tid & 63, h = (tid2 >> 6);                   // h in [0,6)
    char* W = SM + wsel * WREG;
    unsigned short (*ATT)[49][ATS2] = (unsigned short(*)[49][ATS2])W;
    float (*xoT)[196] = (float(*)[196])(W + XOT_OFF);

    int w = blockIdx.x * 2 + wsel, widx = w & 63;
    int wi = widx >> 3, wj = widx & 7, bb = w >> 6;
    const long rowbase = (long)w * 49;
    const bool bdry = (wi == 7) || (wj == 7);

    // ---- Phase 1: LN1 + roll(-3,-3) gather -> lA (rows 0..48, swizzled) ----
    if (tid2 < 196) {
        int r = tid2 >> 2, c0 = (tid2 & 3) * 48;
        int rr = r / 7, ss = r - rr * 7;
        int hh = wi * 7 + rr + 3; if (hh >= 56) hh -= 56;
        int ww = wj * 7 + ss + 3; if (ww >= 56) ww -= 56;
        const f32x4* sp = (const f32x4*)(x + ((long)(bb * 56 + hh) * 56 + ww) * 192 + c0);
        f32x4 vv[12];
        float sum = 0.f, sq = 0.f;
        #pragma unroll
        for (int i = 0; i < 12; i++) {
            vv[i] = sp[i];
            #pragma unroll
            for (int j = 0; j < 4; j++) { sum += vv[i][j]; sq += vv[i][j] * vv[i][j]; }
        }
        sum += __shfl_xor(sum, 1); sq += __shfl_xor(sq, 1);
        sum += __shfl_xor(sum, 2); sq += __shfl_xor(sq, 2);
        float mu = sum * (1.f / 192.f);
        float rs = rsqrtf(sq * (1.f / 192.f) - mu * mu + 1e-5f);
        #pragma unroll
        for (int i = 0; i < 6; i++) {
            bf16x8 o8;
            #pragma unroll
            for (int j = 0; j < 8; j++) {
                int idx = i * 8 + j, c = c0 + idx;
                o8[j] = (short)f2bf((vv[idx >> 2][idx & 3] - mu) * rs * n1g[c] + n1b[c]);
            }
            *(bf16x8*)(W + r * 384 + ((2 * (c0 + i * 8)) ^ ((r & 7) << 4))) = o8;
        }
    }
    __syncthreads();

    // ---- Phase 2: QKV GEMM; wave h computes head h's 32 cols of q,k,v ----
    f32x4 aq[4][2], ak[4][2], av[4][2];
    #pragma unroll
    for (int mi = 0; mi < 4; mi++)
        #pragma unroll
        for (int ni = 0; ni < 2; ni++) {
            aq[mi][ni] = (f32x4){0.f, 0.f, 0.f, 0.f};
            ak[mi][ni] = (f32x4){0.f, 0.f, 0.f, 0.f};
            av[mi][ni] = (f32x4){0.f, 0.f, 0.f, 0.f};
        }
    #pragma unroll
    for (int ks = 0; ks < 6; ks++) {
        int kb = ks * 64 + ((lane >> 4) << 4);
        bf16x8 afr[4];
        #pragma unroll
        for (int mi = 0; mi < 4; mi++) {
            int row = mi * 16 + (lane & 15);                 // rows 49..63 read garbage (outputs discarded)
            afr[mi] = *(const bf16x8*)(W + row * 384 + (kb ^ ((row & 7) << 4)));
        }
        bf16x8 bq[2], bk[2], bv[2];
        #pragma unroll
        for (int ni = 0; ni < 2; ni++) {
            bq[ni] = *(const bf16x8*)(qkvp + (((((0 * 6 + h) * 2 + ni) * 6 + ks)) << 9) + (lane << 3));
            bk[ni] = *(const bf16x8*)(qkvp + (((((1 * 6 + h) * 2 + ni) * 6 + ks)) << 9) + (lane << 3));
            bv[ni] = *(const bf16x8*)(qkvp + (((((2 * 6 + h) * 2 + ni) * 6 + ks)) << 9) + (lane << 3));
        }
        #pragma unroll
        for (int mi = 0; mi < 4; mi++)
            #pragma unroll
            for (int ni = 0; ni < 2; ni++) {
                aq[mi][ni] = __builtin_amdgcn_mfma_f32_16x16x32_bf16(afr[mi], bq[ni], aq[mi][ni], 0, 0, 0);
                ak[mi][ni] = __builtin_amdgcn_mfma_f32_16x16x32_bf16(afr[mi], bk[ni], ak[mi][ni], 0, 0, 0);
                av[mi][ni] = __builtin_amdgcn_mfma_f32_16x16x32_bf16(afr[mi], bv[ni], av[mi][ni], 0, 0, 0);
            }
    }
    __syncthreads();     // lA reads complete; region reusable for qL

    // epilogue: d_out f32 (required outputs) + bf16 LDS copies (qL over lA, kL, vL)
    #pragma unroll
    for (int mi = 0; mi < 4; mi++)
        #pragma unroll
        for (int ni = 0; ni < 2; ni++) {
            int col = h * 32 + ni * 16 + (lane & 15);
            float bgq = qbias[col], bgk = qbias[192 + col], bgv = qbias[384 + col];
            #pragma unroll
            for (int r = 0; r < 4; r++) {
                int m = mi * 16 + ((lane >> 4) << 2) + r;
                if (m < 49) {
                    long gr = (rowbase + m) * 192 + col;
                    float fq = aq[mi][ni][r] + bgq;
                    float fk = ak[mi][ni][r] + bgk;
                    float fv = av[mi][ni][r] + bgv;
                    outq[gr] = fq; outq[OUTCH + gr] = fk; outq[2 * OUTCH + gr] = fv;
                    int sw = (2 * col) ^ ((m & 7) << 4);
                    *(unsigned short*)(W + m * 384 + sw) = f2bf(fq);
                    *(unsigned short*)(W + KL_OFF + m * 384 + sw) = f2bf(fk);
                    *(unsigned short*)(W + VL_OFF + m * 404 + 2 * col) = f2bf(fv);
                }
            }
        }
    __syncthreads();

    // ---- Phase 4a: QK^T fragments from qL/kL -> sa in registers ----
    bf16x8 qfr[4], kfr[4];
    #pragma unroll
    for (int mi = 0; mi < 4; mi++) {
        int m = mi * 16 + (lane & 15); if (m > 48) m = 48;
        qfr[mi] = *(const bf16x8*)(W + m * 384 + ((h * 64 + ((lane >> 4) << 4)) ^ ((m & 7) << 4)));
    }
    #pragma unroll
    for (int ni = 0; ni < 4; ni++) {
        int n = ni * 16 + (lane & 15); if (n > 48) n = 48;
        kfr[ni] = *(const bf16x8*)(W + KL_OFF + n * 384 + ((h * 64 + ((lane >> 4) << 4)) ^ ((n & 7) << 4)));
    }
    f32x4 sa[4][4];
    #pragma unroll
    for (int ni = 0; ni < 4; ni++)
        #pragma unroll
        for (int mi = 0; mi < 4; mi++)
            sa[mi][ni] = __builtin_amdgcn_mfma_f32_16x16x32_bf16(qfr[mi], kfr[ni], (f32x4){0.f, 0.f, 0.f, 0.f}, 0, 0, 0);
    __syncthreads();     // qL/kL dead; ATT region fresh

    // ---- Phase 4b: zero ATT pad cols [49,64) + write scores (bf16) ----
    for (int c = tid2; c < 6 * 49 * 15; c += 384) {
        int g = c / (49 * 15), rem = c - g * (49 * 15);
        int m = rem / 15, n = 49 + (rem - m * 15);
        ATT[g][m][n] = 0;
    }
    const float scale = 0.17677669529663687f;   // 32^-0.5
    #pragma unroll
    for (int mi = 0; mi < 4; mi++)
        #pragma unroll
        for (int ni = 0; ni < 4; ni++)
            #pragma unroll
            for (int r = 0; r < 4; r++) {
                int m = mi * 16 + ((lane >> 4) << 2) + r, n = ni * 16 + (lane & 15);
                if (m < 49 && n < 49) {
                    int rq = m / 7, cq = m - rq * 7, rk = n / 7, ck = n - rk * 7;
                    int ridx = (rq - rk + 6) * 13 + (cq - ck + 6);
                    ATT[h][m][n] = f2bf(sa[mi][ni][r] * scale + rpb[ridx * 6 + h]);
                }
            }
    __syncthreads();

    // ---- Phase 5: pl head-mix + shift mask (in place; interior windows skip mask) ----
    for (int p = tid2; p < 2401; p += 384) {
        int m = p / 49, n = p - m * 49;
        float a[6];
        #pragma unroll
        for (int g = 0; g < 6; g++) a[g] = bf2f(ATT[g][m][n]);
        float msk = 0.f;
        if (bdry) {
            int rq = m / 7, cq = m - rq * 7, rk = n / 7, ck = n - rk * 7;
            int ghq = wi * 7 + rq, gwq = wj * 7 + cq, ghk = wi * 7 + rk, gwk = wj * 7 + ck;
            int regq = (ghq < 49 ? 0 : (ghq < 53 ? 1 : 2)) * 3 + (gwq < 49 ? 0 : (gwq < 53 ? 1 : 2));
            int regk = (ghk < 49 ? 0 : (ghk < 53 ? 1 : 2)) * 3 + (gwk < 49 ? 0 : (gwk < 53 ? 1 : 2));
            msk = (regq != regk) ? -100.f : 0.f;
        }
        #pragma unroll
        for (int g = 0; g < 6; g++) {
            float v = plb[g] + msk;
            #pragma unroll
            for (int h2i = 0; h2i < 6; h2i++) v += a[h2i] * plw[h2i * 6 + g];
            ATT[g][m][n] = f2bf(v);
        }
    }
    __syncthreads();

    // ---- Phase 6: softmax, row-per-lane ----
    if (tid2 < 294) {
        int g = tid2 / 49, m = tid2 - g * 49;
        unsigned short* row = &ATT[g][m][0];
        float mx = bf2f(row[0]);
        #pragma unroll
        for (int j = 1; j < 49; j++) mx = fmaxf(mx, bf2f(row[j]));
        float e[49]; float sm = 0.f;
        #pragma unroll
        for (int j = 0; j < 49; j++) { e[j] = __expf(bf2f(row[j]) - mx); sm += e[j]; }
        float inv = 1.f / sm;
        #pragma unroll
        for (int j = 0; j < 49; j++) row[j] = f2bf(e[j] * inv);
    }
    __syncthreads();

    // ---- Phase 7: pw head-mix (in place) ----
    for (int p = tid2; p < 2401; p += 384) {
        int m = p / 49, n = p - m * 49;
        float a[6];
        #pragma unroll
        for (int g = 0; g < 6; g++) a[g] = bf2f(ATT[g][m][n]);
        #pragma unroll
        for (int g = 0; g < 6; g++) {
            float v = pwb[g];
            #pragma unroll
            for (int h2i = 0; h2i < 6; h2i++) v += a[h2i] * pww[h2i * 6 + g];
            ATT[g][m][n] = f2bf(v);
        }
    }
    __syncthreads();

    // ---- Phase 8: PV (P-frags from ATT b128, V-frags from vL) ----
    bf16x8 vfr[2][2];
    #pragma unroll
    for (int kst = 0; kst < 2; kst++)
        #pragma unroll
        for (int ni = 0; ni < 2; ni++) {
            int d = h * 32 + ni * 16 + (lane & 15);
            #pragma unroll
            for (int j = 0; j < 8; j++) {
                int n = kst * 32 + ((lane >> 4) << 3) + j; if (n > 48) n = 48;
                vfr[kst][ni][j] = *(const unsigned short*)(W + VL_OFF + n * 404 + 2 * d);
            }
        }
    f32x4 oa[4][2];
    #pragma unroll
    for (int mi = 0; mi < 4; mi++)
        #pragma unroll
        for (int ni = 0; ni < 2; ni++) oa[mi][ni] = (f32x4){0.f, 0.f, 0.f, 0.f};
    #pragma unroll
    for (int kst = 0; kst < 2; kst++) {
        #pragma unroll
        for (int mi = 0; mi < 4; mi++) {
            int m = mi * 16 + (lane & 15); if (m > 48) m = 48;
            bf16x8 afr = *(const bf16x8*)&ATT[h][m][kst * 32 + ((lane >> 4) << 3)];
            #pragma unroll
            for (int ni = 0; ni < 2; ni++)
                oa[mi][ni] = __builtin_amdgcn_mfma_f32_16x16x32_bf16(afr, vfr[kst][ni], oa[mi][ni], 0, 0, 0);
        }
    }
    __syncthreads();                         // ATT + vL dead; region reusable

    // ---- Phase 9: PV-out -> PO (bf16, swizzled) at [0,18816) ----
    #pragma unroll
    for (int mi = 0; mi < 4; mi++)
        #pragma unroll
        for (int ni = 0; ni < 2; ni++)
            #pragma unroll
            for (int r = 0; r < 4; r++) {
                int m = mi * 16 + ((lane >> 4) << 2) + r;
                if (m < 49) {
                    int col = h * 32 + ni * 16 + (lane & 15);
                    *(unsigned short*)(W + m * 384 + ((2 * col) ^ ((m & 7) << 4))) = f2bf(oa[mi][ni][r]);
                }
            }
    __syncthreads();

    // ---- Phase 10: proj GEMM (wave h -> cols h*32..+32) ----
    f32x4 pacc[4][2];
    #pragma unroll
    for (int mi = 0; mi < 4; mi++)
        #pragma unroll
        for (int ni = 0; ni < 2; ni++) pacc[mi][ni] = (f32x4){0.f, 0.f, 0.f, 0.f};
    #pragma unroll
    for (int ks = 0; ks < 6; ks++) {
        int kb = ks * 64 + ((lane >> 4) << 4);
        bf16x8 bfr[2];
        #pragma unroll
        for (int ni = 0; ni < 2; ni++) {
            int instr = (h * 2 + ni) * 6 + ks;
            bfr[ni] = *(const bf16x8*)(projp + (instr << 9) + (lane << 3));
        }
        #pragma unroll
        for (int mi = 0; mi < 4; mi++) {
            int row = mi * 16 + (lane & 15); if (row > 48) row = 48;
            bf16x8 afr = *(const bf16x8*)(W + row * 384 + (kb ^ ((row & 7) << 4)));
            #pragma unroll
            for (int ni = 0; ni < 2; ni++)
                pacc[mi][ni] = __builtin_amdgcn_mfma_f32_16x16x32_bf16(afr, bfr[ni], pacc[mi][ni], 0, 0, 0);
        }
    }

    // ---- Phase 11: residual gather xoT[m][gc] = x[spatial] + proj + pbias ----
    #pragma unroll
    for (int mi = 0; mi < 4; mi++)
        #pragma unroll
        for (int ni = 0; ni < 2; ni++) {
            int gc = h * 32 + ni * 16 + (lane & 15);
            float bv = pbias[gc];
            #pragma unroll
            for (int r = 0; r < 4; r++) {
                int m = mi * 16 + ((lane >> 4) << 2) + r;
                if (m < 49) {
                    int rr = m / 7, ss = m - rr * 7;
                    int ho = wi * 7 + rr + 3; if (ho >= 56) ho -= 56;     // roll(+SHIFT)
                    int wo = wj * 7 + ss + 3; if (wo >= 56) wo -= 56;
                    long tp = ((long)(bb * 56 + ho) * 56 + wo);
                    xoT[m][gc] = x[tp * 192 + gc] + pacc[mi][ni][r] + bv;
                }
            }
        }
    __syncthreads();

    // ---- Phase 12: LN2 + spatial writes of h2 and xv (bf16) ----
    if (tid2 < 196) {
        int m = tid2 >> 2, c0 = (tid2 & 3) * 48;
        float vv[48];
        float sum = 0.f, sq = 0.f;
        #pragma unroll
        for (int i = 0; i < 48; i++) { vv[i] = xoT[m][c0 + i]; sum += vv[i]; sq += vv[i] * vv[i]; }
        sum += __shfl_xor(sum, 1); sq += __shfl_xor(sq, 1);
        sum += __shfl_xor(sum, 2); sq += __shfl_xor(sq, 2);
        float mu = sum * (1.f / 192.f);
        float rs = rsqrtf(sq * (1.f / 192.f) - mu * mu + 1e-5f);
        int rr = m / 7, ss = m - rr * 7;
        int ho = wi * 7 + rr + 3; if (ho >= 56) ho -= 56;
        int wo = wj * 7 + ss + 3; if (wo >= 56) wo -= 56;
        long tp = ((long)(bb * 56 + ho) * 56 + wo);
        #pragma unroll
        for (int i = 0; i < 6; i++) {
            bf16x8 o8, x8;
            #pragma unroll
            for (int j = 0; j < 8; j++) {
                int c = c0 + i * 8 + j;
                float xvf = vv[i * 8 + j];
                x8[j] = (short)f2bf(xvf);
                o8[j] = (short)f2bf((xvf - mu) * rs * g2[c] + b2[c]);
            }
            *(bf16x8*)(h2 + tp * 192 + c0 + i * 8) = o8;
            *(bf16x8*)(xv + tp * 192 + c0 + i * 8) = x8;
        }
    }
}

// ---------------- launcher ----------------
extern "C" void kernel_launch(void* const* d_in, const int* in_sizes, int n_in,
                              void* d_out, int out_size, void* d_ws, size_t ws_size,
                              hipStream_t stream)
{
    const float* x      = (const float*)d_in[0];
    const float* n1g    = (const float*)d_in[1];
    const float* n1b    = (const float*)d_in[2];
    const float* qkv_w  = (const float*)d_in[3];
    const float* qkv_b  = (const float*)d_in[4];
    const float* proj_w = (const float*)d_in[5];
    const float* proj_b = (const float*)d_in[6];
    const float* rpb    = (const float*)d_in[7];
    const float* pl_w   = (const float*)d_in[8];
    const float* pl_b   = (const float*)d_in[9];
    const float* pw_w   = (const float*)d_in[10];
    const float* pw_b   = (const float*)d_in[11];
    const float* n2g    = (const float*)d_in[12];
    const float* n2b    = (const float*)d_in[13];
    const float* fc1_w  = (const float*)d_in[14];
    const float* fc1_b  = (const float*)d_in[15];
    const float* fc2_w  = (const float*)d_in[16];
    const float* fc2_b  = (const float*)d_in[17];

    float* out   = (float*)d_out;   // f32: [xo | q | k | v], each OUTCH elements
    float* out_q = out + OUTCH;

    // ws: bufT (h2) 38,535,168 | xvB 38,535,168 | bufW 884,736
    char* ws = (char*)d_ws;
    unsigned short* bufT = (unsigned short*)ws;
    unsigned short* xvB  = (unsigned short*)(ws + 38535168);
    unsigned short* bufW = (unsigned short*)(ws + 2 * 38535168L);

    k_prep_w<<<1728, 256, 0, stream>>>(qkv_w, proj_w, fc1_w, fc2_w, bufW);
    k_attn<<<NWIN / 2, 768, 0, stream>>>(x, n1g, n1b, bufW, qkv_b,
                                         rpb, pl_w, pl_b, pw_w, pw_b,
                                         bufW + 110592, proj_b, n2g, n2b,
                                         out_q, xvB, bufT);                   // q/k/v + h2 + xv
    k_mlp<<<1568, 256, 0, stream>>>(bufT, bufW + 147456, fc1_b, bufW + 294912, fc2_b,
                                    xvB, out);
}